// Round 1
// 2394.390 us; speedup vs baseline: 1.0058x; 1.0058x over previous
//
#include <hip/hip_runtime.h>
#include <cstdint>
#include <cstddef>

typedef unsigned short u16;
typedef __bf16 bf16x8 __attribute__((ext_vector_type(8)));
typedef float f32x4 __attribute__((ext_vector_type(4)));

// ---------- helpers ----------

__device__ __forceinline__ u16 f2bf(float f) {
  unsigned u = __builtin_bit_cast(unsigned, f);
  u += 0x7fffu + ((u >> 16) & 1u);   // round-to-nearest-even
  return (u16)(u >> 16);
}

__device__ __forceinline__ void gld16(const u16* g, u16* l) {
  // async global->LDS, 16B per lane; LDS dest = wave-uniform base + lane*16
  __builtin_amdgcn_global_load_lds((__attribute__((address_space(1))) void*)(g),
                                   (__attribute__((address_space(3))) void*)(l),
                                   16, 0, 0);
}

// ---------- prep kernels ----------

__global__ void gather_x(const float* __restrict__ x,
                         const int* __restrict__ svd_up, const int* __restrict__ col_up,
                         const int* __restrict__ svd_gate, const int* __restrict__ col_gate,
                         u16* __restrict__ XG, u16* __restrict__ Afused) {
  const int r = blockIdx.x;
  const float* xr = x + (size_t)r * 4096;
  const int* idx; u16* dst; int n;
  switch (blockIdx.y) {
    case 0:  idx = svd_up;   dst = XG + (size_t)r * 6144;            n = 3072; break;
    case 1:  idx = svd_gate; dst = XG + (size_t)r * 6144 + 3072;     n = 3072; break;
    case 2:  idx = col_up;   dst = Afused + (size_t)r * 4096 + 1024; n = 1024; break;
    default: idx = col_gate; dst = Afused + (size_t)r * 4096 + 3072; n = 1024; break;
  }
  for (int j = threadIdx.x; j < n; j += 256) dst[j] = f2bf(xr[idx[j]]);
}

__global__ void cast_bf16_vec(const float* __restrict__ src, u16* __restrict__ dst, int n4) {
  int i = blockIdx.x * 256 + threadIdx.x;
  if (i < n4) {
    float4 f = ((const float4*)src)[i];
    ushort4 o;
    o.x = f2bf(f.x); o.y = f2bf(f.y); o.z = f2bf(f.z); o.w = f2bf(f.w);
    ((ushort4*)dst)[i] = o;
  }
}

__global__ void build_wfused(const float* __restrict__ up_u, const float* __restrict__ up_c,
                             const float* __restrict__ gate_u, const float* __restrict__ gate_c,
                             const int* __restrict__ svd_down, const int* __restrict__ col_down,
                             u16* __restrict__ W) {
  const int j = blockIdx.x;
  const int c = (j < 8192) ? svd_down[j] : col_down[j - 8192];
  const float* s0 = up_u   + (size_t)c * 1024;
  const float* s1 = up_c   + (size_t)c * 1024;
  const float* s2 = gate_u + (size_t)c * 1024;
  const float* s3 = gate_c + (size_t)c * 1024;
  u16* w = W + (size_t)j * 4096;
  for (int t = threadIdx.x; t < 1024; t += 256) {
    w[t]        = f2bf(s0[t]);
    w[1024 + t] = f2bf(s1[t]);
    w[2048 + t] = f2bf(s2[t]);
    w[3072 + t] = f2bf(s3[t]);
  }
}

__global__ void build_wdown2(const float* __restrict__ down_u, const float* __restrict__ down_c,
                             u16* __restrict__ W) {
  const int o = blockIdx.x;
  const float* s0 = down_u + (size_t)o * 1024;
  const float* s1 = down_c + (size_t)o * 2816;
  u16* w = W + (size_t)o * 3840;
  for (int t = threadIdx.x; t < 1024; t += 256) w[t] = f2bf(s0[t]);
  for (int t = threadIdx.x; t < 2816; t += 256) w[1024 + t] = f2bf(s1[t]);
}

// ---------- GEMM engine: 256x128 tile, BK=64, 8 waves (4Mx2N), double-buffered,
// 2 phases/K-tile, counted vmcnt(6), XOR bank-swizzled LDS (both-sides), setprio ----
//
// C = A * B^T. A row-major [M,K] ld=lda (u16/bf16), B row-major [N,K] ld=ldb.
// EPI 0: bf16 out at C (ldc, col offset coff). EPI 1: f32 out. EPI 2: fused SwiGLU
// (dual accumulator: K-tiles [0,nt/2) -> U, [nt/2,nt) -> G; out routed Gsvd/Afin).
//
// LDS layout: A buffers [2][256][64] bf16 (row stride 128B), B [2][128][64].
// Swizzle: 16B granule g at row r holds logical granule g ^ (r&7). Staged by
// pre-swizzling the per-lane GLOBAL source (LDS dest stays linear, as required
// by global_load_lds); ds_read applies the same XOR -> conflict-free (8 words/bank).
//
// Pipeline per K-tile t (buffer p = t&1):
//  P0: ds_read ks0 frags (8); setprio(1); 16 MFMA; setprio(0); s_barrier
//  P1: ds_read ks1 frags (8); lgkmcnt(0); s_barrier   <- all reads of buf p retired
//      issue 6 global_load_lds for tile t+2 -> buf p   (window ~2 phases)
//      setprio(1); 16 MFMA; setprio(0); vmcnt(6) [never 0 mid-loop]; s_barrier
template <int EPI>
__global__ __launch_bounds__(512, 2) void gemm256(
    const u16* __restrict__ A, int lda,
    const u16* __restrict__ B, int ldb, int K,
    void* __restrict__ C, int ldc, int coff,
    u16* __restrict__ C2) {
  __shared__ u16 As[2 * 16384];   // 64 KB
  __shared__ u16 Bs[2 * 8192];    // 32 KB

  int bx, by;
  if constexpr (EPI == 2) {
    // L3-locality swizzle: groups of 16 row-tiles; B sweep advances every 16 blocks.
    const int GRP = 16, NX = 86, per = NX * GRP;
    const int bid = blockIdx.x;
    const int g = bid / per, rem = bid % per;
    bx = rem / GRP; by = g * GRP + rem % GRP;
  } else {
    bx = blockIdx.x; by = blockIdx.y;
  }

  const int tid = threadIdx.x;
  const int wave = tid >> 6, lane = tid & 63;
  const int quad = lane >> 4, l16 = lane & 15;
  const int wm = wave & 3, wn = wave >> 2;       // 4x2 wave grid, per-wave 64x64
  const int row0 = by * 256, col0 = bx * 128;

  // staging coords: thread covers row (j*64 + rst), phys granule (tid&7);
  // source logical granule = phys ^ (row&7) = (tid&7) ^ ((tid>>3)&7)
  const int rst = tid >> 3;
  const int gst = (tid & 7) ^ ((tid >> 3) & 7);
  const u16* gA = A + (size_t)(row0 + rst) * lda + gst * 8;
  const u16* gB = B + (size_t)(col0 + rst) * ldb + gst * 8;
  u16* sA = As + wave * 512;
  u16* sB = Bs + wave * 512;

  const int nt = K >> 6;
  const int xr = l16 & 7;

#define STAGE(t)                                                         \
  {                                                                      \
    const int tg_ = (t) & 1;                                             \
    const u16* ga_ = gA + (size_t)(t) * 64;                              \
    u16* da_ = sA + tg_ * 16384;                                         \
    _Pragma("unroll") for (int j = 0; j < 4; ++j)                        \
        gld16(ga_ + (size_t)j * 64 * lda, da_ + j * 4096);               \
    const u16* gb_ = gB + (size_t)(t) * 64;                              \
    u16* db_ = sB + tg_ * 8192;                                          \
    _Pragma("unroll") for (int j = 0; j < 2; ++j)                        \
        gld16(gb_ + (size_t)j * 64 * ldb, db_ + j * 4096);               \
  }

  // frag load: row = strip*64 + i*16 + l16, phys granule = (ks*4+quad)^(l16&7)
#define LDFRAG(dst, base, strip, i, ks)                                       \
  dst = *(const bf16x8*)&(base)[((strip) * 64 + (i) * 16 + l16) * 64 +        \
                                ((((ks) * 4 + quad) ^ xr) * 8)];

  f32x4 accU[4][4] = {};
  f32x4 accG[4][4] = {};

  // prologue: tiles 0 and 1 in flight; wait tile 0 (6 newest = tile 1 outstanding)
  STAGE(0)
  if (nt > 1) STAGE(1)
  asm volatile("s_waitcnt vmcnt(6)" ::: "memory");
  __builtin_amdgcn_s_barrier();

#define TILE_STEP(ACC, t)                                                     \
  {                                                                           \
    const u16* As_ = As + ((t) & 1) * 16384;                                  \
    const u16* Bs_ = Bs + ((t) & 1) * 8192;                                   \
    bf16x8 a0[4], b0[4];                                                      \
    _Pragma("unroll") for (int i = 0; i < 4; ++i) LDFRAG(a0[i], As_, wm, i, 0)\
    _Pragma("unroll") for (int i = 0; i < 4; ++i) LDFRAG(b0[i], Bs_, wn, i, 0)\
    __builtin_amdgcn_s_setprio(1);                                            \
    _Pragma("unroll") for (int mi = 0; mi < 4; ++mi)                          \
      _Pragma("unroll") for (int ni = 0; ni < 4; ++ni)                        \
        ACC[mi][ni] = __builtin_amdgcn_mfma_f32_16x16x32_bf16(                \
            a0[mi], b0[ni], ACC[mi][ni], 0, 0, 0);                            \
    __builtin_amdgcn_s_setprio(0);                                            \
    __builtin_amdgcn_s_barrier();                                             \
    bf16x8 a1[4], b1[4];                                                      \
    _Pragma("unroll") for (int i = 0; i < 4; ++i) LDFRAG(a1[i], As_, wm, i, 1)\
    _Pragma("unroll") for (int i = 0; i < 4; ++i) LDFRAG(b1[i], Bs_, wn, i, 1)\
    asm volatile("s_waitcnt lgkmcnt(0)" ::: "memory");                        \
    __builtin_amdgcn_s_barrier();                                             \
    if ((t) + 2 < nt) STAGE((t) + 2)                                          \
    __builtin_amdgcn_sched_barrier(0);                                        \
    __builtin_amdgcn_s_setprio(1);                                            \
    _Pragma("unroll") for (int mi = 0; mi < 4; ++mi)                          \
      _Pragma("unroll") for (int ni = 0; ni < 4; ++ni)                        \
        ACC[mi][ni] = __builtin_amdgcn_mfma_f32_16x16x32_bf16(                \
            a1[mi], b1[ni], ACC[mi][ni], 0, 0, 0);                            \
    __builtin_amdgcn_s_setprio(0);                                            \
    __builtin_amdgcn_sched_barrier(0);                                        \
    if ((t) + 2 < nt)                                                         \
      asm volatile("s_waitcnt vmcnt(6)" ::: "memory");                        \
    else                                                                      \
      asm volatile("s_waitcnt vmcnt(0)" ::: "memory");                        \
    __builtin_amdgcn_s_barrier();                                             \
  }

  const int nt1 = (EPI == 2) ? (nt >> 1) : nt;
  for (int t = 0; t < nt1; ++t) TILE_STEP(accU, t)
  if constexpr (EPI == 2) {
    for (int t = nt1; t < nt; ++t) TILE_STEP(accG, t)
  }

  // ---------- epilogue ----------
  if constexpr (EPI == 2) {
    u16* outp; int ldo, c2;
    if (col0 < 8192) { outp = (u16*)C; ldo = 8192; c2 = col0; }
    else             { outp = C2;      ldo = 3840; c2 = 1024 + (col0 - 8192); }
#pragma unroll
    for (int mi = 0; mi < 4; ++mi)
#pragma unroll
      for (int ni = 0; ni < 4; ++ni)
#pragma unroll
        for (int r = 0; r < 4; ++r) {
          const float u = accU[mi][ni][r];
          const float gg = accG[mi][ni][r];
          const float val = u * gg / (1.0f + __expf(-gg));  // silu(g)*u
          const int gm = row0 + wm * 64 + mi * 16 + quad * 4 + r;
          const int gn = c2 + wn * 64 + ni * 16 + l16;
          outp[(size_t)gm * ldo + gn] = f2bf(val);
        }
  } else {
#pragma unroll
    for (int mi = 0; mi < 4; ++mi)
#pragma unroll
      for (int ni = 0; ni < 4; ++ni)
#pragma unroll
        for (int r = 0; r < 4; ++r) {
          const int gm = row0 + wm * 64 + mi * 16 + quad * 4 + r;
          const int gn = coff + col0 + wn * 64 + ni * 16 + l16;
          if constexpr (EPI == 0)
            ((u16*)C)[(size_t)gm * ldc + gn] = f2bf(accU[mi][ni][r]);
          else
            ((float*)C)[(size_t)gm * ldc + gn] = accU[mi][ni][r];
        }
  }
#undef STAGE
#undef LDFRAG
#undef TILE_STEP
}

// ---------- launch ----------

extern "C" void kernel_launch(void* const* d_in, const int* in_sizes, int n_in,
                              void* d_out, int out_size, void* d_ws, size_t ws_size,
                              hipStream_t stream) {
  const float* x      = (const float*)d_in[0];
  const float* up_v   = (const float*)d_in[1];
  const float* up_u   = (const float*)d_in[2];
  const float* up_c   = (const float*)d_in[3];
  const float* gate_v = (const float*)d_in[4];
  const float* gate_u = (const float*)d_in[5];
  const float* gate_c = (const float*)d_in[6];
  const float* down_v = (const float*)d_in[7];
  const float* down_u = (const float*)d_in[8];
  const float* down_c = (const float*)d_in[9];
  const int* svd_up   = (const int*)d_in[10];
  const int* col_up   = (const int*)d_in[11];
  const int* svd_gate = (const int*)d_in[12];
  const int* col_gate = (const int*)d_in[13];
  const int* svd_down = (const int*)d_in[14];
  const int* col_down = (const int*)d_in[15];

  char* ws = (char*)d_ws;
  // XG [8192,6144] (100.7MB) aliases Gsvd [8192,8192] (134.2MB): XG dead before Gsvd written.
  u16* XG     = (u16*)(ws + 0);
  u16* Gsvd   = (u16*)(ws + 0);
  u16* Afused = (u16*)(ws + 134217728);  // [8192,4096] 67.1MB
  u16* Afin   = (u16*)(ws + 201326592);  // [8192,3840] 62.9MB
  u16* V1     = (u16*)(ws + 264241152);  // [2048,3072] 12.6MB  (V1u rows 0:1024, V1g rows 1024:2048)
  u16* Wf     = (u16*)(ws + 276824064);  // [11008,4096] 90.2MB
  u16* DV     = (u16*)(ws + 367001600);  // [1024,8192] 16.8MB
  u16* W2     = (u16*)(ws + 383778816);  // [4096,3840] 31.5MB  (total ~396MiB)

  const dim3 blk(256);
  const dim3 blk512(512);
  // phase 0: gathers + weight prep (independent)
  gather_x<<<dim3(8192, 4), blk, 0, stream>>>(x, svd_up, col_up, svd_gate, col_gate, XG, Afused);
  cast_bf16_vec<<<dim3(3072), blk, 0, stream>>>(up_v, V1, 1024 * 3072 / 4);
  cast_bf16_vec<<<dim3(3072), blk, 0, stream>>>(gate_v, V1 + 1024 * 3072, 1024 * 3072 / 4);
  cast_bf16_vec<<<dim3(8192), blk, 0, stream>>>(down_v, DV, 1024 * 8192 / 4);
  build_wfused<<<dim3(11008), blk, 0, stream>>>(up_u, up_c, gate_u, gate_c, svd_down, col_down, Wf);
  build_wdown2<<<dim3(4096), blk, 0, stream>>>(down_u, down_c, W2);

  // phase 1: t_up / t_gate (M=8192, N=1024, K=3072) -> Afused cols 0:1024 & 2048:3072
  gemm256<0><<<dim3(8, 32), blk512, 0, stream>>>(XG, 6144, V1, 3072, 3072, Afused, 4096, 0, nullptr);
  gemm256<0><<<dim3(8, 32), blk512, 0, stream>>>(XG + 3072, 6144, V1 + 1024 * 3072, 3072, 3072, Afused, 4096, 2048, nullptr);

  // phase 2: fused up/gate stage-2 + SwiGLU (M=8192, N=11008, K=2048+2048), swizzled grid
  gemm256<2><<<dim3(86 * 32), blk512, 0, stream>>>(Afused, 4096, Wf, 4096, 4096, Gsvd, 0, 0, Afin);

  // phase 3: t2 = Gsvd @ down_v^T (M=8192, N=1024, K=8192) -> Afin cols 0:1024
  gemm256<0><<<dim3(8, 32), blk512, 0, stream>>>(Gsvd, 8192, DV, 8192, 8192, Afin, 3840, 0, nullptr);

  // phase 4: out = Afin @ W2^T (M=8192, N=4096, K=3840), fp32 -> d_out
  gemm256<1><<<dim3(32, 32), blk512, 0, stream>>>(Afin, 3840, W2, 3840, 3840, d_out, 4096, 0, nullptr);
}

// Round 2
// 1830.396 us; speedup vs baseline: 1.3158x; 1.3081x over previous
//
#include <hip/hip_runtime.h>
#include <cstdint>
#include <cstddef>

typedef unsigned short u16;
typedef __bf16 bf16x8 __attribute__((ext_vector_type(8)));
typedef float f32x4 __attribute__((ext_vector_type(4)));

// ---------- helpers ----------

__device__ __forceinline__ u16 f2bf(float f) {
  unsigned u = __builtin_bit_cast(unsigned, f);
  u += 0x7fffu + ((u >> 16) & 1u);   // round-to-nearest-even
  return (u16)(u >> 16);
}

__device__ __forceinline__ void gld16(const u16* g, u16* l) {
  // async global->LDS, 16B per lane; LDS dest = wave-uniform base + lane*16
  __builtin_amdgcn_global_load_lds((__attribute__((address_space(1))) void*)(g),
                                   (__attribute__((address_space(3))) void*)(l),
                                   16, 0, 0);
}

// ---------- prep kernels ----------

// One block per row: stage the full 16KB x-row in LDS (coalesced float4 reads),
// then scatter-read LDS for all four gathers -> x fetched exactly once.
__global__ void gather_x2(const float* __restrict__ x,
                          const int* __restrict__ svd_up, const int* __restrict__ col_up,
                          const int* __restrict__ svd_gate, const int* __restrict__ col_gate,
                          u16* __restrict__ XG, u16* __restrict__ Afused) {
  __shared__ float row[4096];
  const int r = blockIdx.x;
  const float4* xr = (const float4*)(x + (size_t)r * 4096);
#pragma unroll
  for (int j = 0; j < 4; ++j)
    ((float4*)row)[threadIdx.x + j * 256] = xr[threadIdx.x + j * 256];
  __syncthreads();
  u16* d0 = XG + (size_t)r * 6144;
  u16* d1 = d0 + 3072;
  u16* d2 = Afused + (size_t)r * 4096 + 1024;
  u16* d3 = d2 + 2048;
  for (int j = threadIdx.x; j < 3072; j += 256) d0[j] = f2bf(row[svd_up[j]]);
  for (int j = threadIdx.x; j < 3072; j += 256) d1[j] = f2bf(row[svd_gate[j]]);
  for (int j = threadIdx.x; j < 1024; j += 256) d2[j] = f2bf(row[col_up[j]]);
  for (int j = threadIdx.x; j < 1024; j += 256) d3[j] = f2bf(row[col_gate[j]]);
}

__global__ void cast_bf16_vec(const float* __restrict__ src, u16* __restrict__ dst, int n4) {
  int i = blockIdx.x * 256 + threadIdx.x;
  if (i < n4) {
    float4 f = ((const float4*)src)[i];
    ushort4 o;
    o.x = f2bf(f.x); o.y = f2bf(f.y); o.z = f2bf(f.z); o.w = f2bf(f.w);
    ((ushort4*)dst)[i] = o;
  }
}

__global__ void build_wfused(const float* __restrict__ up_u, const float* __restrict__ up_c,
                             const float* __restrict__ gate_u, const float* __restrict__ gate_c,
                             const int* __restrict__ svd_down, const int* __restrict__ col_down,
                             u16* __restrict__ W) {
  const int j = blockIdx.x;
  const int c = (j < 8192) ? svd_down[j] : col_down[j - 8192];
  const float* s0 = up_u   + (size_t)c * 1024;
  const float* s1 = up_c   + (size_t)c * 1024;
  const float* s2 = gate_u + (size_t)c * 1024;
  const float* s3 = gate_c + (size_t)c * 1024;
  u16* w = W + (size_t)j * 4096;
  for (int t = threadIdx.x; t < 1024; t += 256) {
    w[t]        = f2bf(s0[t]);
    w[1024 + t] = f2bf(s1[t]);
    w[2048 + t] = f2bf(s2[t]);
    w[3072 + t] = f2bf(s3[t]);
  }
}

__global__ void build_wdown2(const float* __restrict__ down_u, const float* __restrict__ down_c,
                             u16* __restrict__ W) {
  const int o = blockIdx.x;
  const float* s0 = down_u + (size_t)o * 1024;
  const float* s1 = down_c + (size_t)o * 2816;
  u16* w = W + (size_t)o * 3840;
  for (int t = threadIdx.x; t < 1024; t += 256) w[t] = f2bf(s0[t]);
  for (int t = threadIdx.x; t < 2816; t += 256) w[1024 + t] = f2bf(s1[t]);
}

// ---------- GEMM engine ----------
// C = A * B^T. A row-major [M,K] ld=lda (bf16 as u16), B row-major [N,K] ld=ldb.
// Tile 256x128, BK=64, 8 waves (4M x 2N), per-wave 64x64 (acc 4x4 f32x4).
// EPI 0: bf16 out; EPI 1: f32 out; EPI 2: fused SwiGLU dual-acc
//   (K-tiles [0,nt/2) -> U, [nt/2,nt) -> G; out routed Gsvd / Afin).
//
// Schedule (m201-style): TRIPLE-buffered LDS slots (tile T -> slot T%3).
// Iteration i computes tiles 2i (slots *0), 2i+1 (slots *1); 4 phases:
//   P1: ds_read a-frags(2i)+b01 | stage A(2i+2)->slot2 | bar | lgkm0 | 16 MFMA | bar
//   P2: ds_read b23             | stage B(2i+2)->slot2 | bar | lgkm0 | 16 MFMA | vmcnt(6) | bar
//   P3: ds_read a-frags(2i+1)+b01 | stage A(2i+3)->slot0 | bar | lgkm0 | 16 MFMA | bar
//   P4: ds_read b23             | stage B(2i+3)->slot0 | bar | lgkm0 | 16 MFMA | vmcnt(6) | bar
//   rotate (s0,s1,s2) <- (s2,s0,s1)
// Stage targets are slots whose last read was >=1 full phase earlier (no race);
// vmcnt(6) leaves exactly the newest tile's 6 loads in flight (2-3 phase slack);
// each vmcnt is followed by s_barrier so other waves' LDS writes are published.
// LDS swizzle: 16B granule g at row r holds logical granule g^(r&7); staged by
// pre-swizzling the per-lane GLOBAL source (LDS dest linear); ds_read applies
// the same XOR -> 0 bank conflicts (verified round 1).
template <int EPI>
__global__ __launch_bounds__(512, 2) void gemm256(
    const u16* __restrict__ A, int lda,
    const u16* __restrict__ B, int ldb, int K,
    void* __restrict__ C, int ldc, int coff, u16* __restrict__ C2,
    const u16* __restrict__ A2, const u16* __restrict__ B2, int nxsplit, int coff2) {
  __shared__ u16 As[3 * 16384];   // 96 KB: 3 slots of [256][64]
  __shared__ u16 Bs[3 * 8192];    // 48 KB: 3 slots of [128][64]

  int bx, by;
  if constexpr (EPI == 2) {
    // L3-locality swizzle: groups of 16 row-tiles; B sweep advances every 16 blocks.
    const int GRP = 16, NX = 86, per = NX * GRP;
    const int bid = blockIdx.x;
    const int g = bid / per, rem = bid % per;
    bx = rem / GRP; by = g * GRP + rem % GRP;
  } else {
    bx = blockIdx.x; by = blockIdx.y;
    if (bx >= nxsplit) { A = A2; B = B2; coff = coff2; bx -= nxsplit; }
  }

  const int tid = threadIdx.x;
  const int wave = tid >> 6, lane = tid & 63;
  const int quad = lane >> 4, l16 = lane & 15;
  const int wm = wave & 3, wn = wave >> 2;       // 4x2 wave grid, per-wave 64x64
  const int row0 = by * 256, col0 = bx * 128;
  const int xr = l16 & 7;

  // staging coords: thread covers row rst (+64j), phys granule (tid&7);
  // global source logical granule = (tid&7) ^ (rst&7)
  const int rst = tid >> 3;
  const int gst8 = ((tid & 7) ^ (rst & 7)) * 8;
  const u16* gA = A + (size_t)(row0 + rst) * lda + gst8;
  const u16* gB = B + (size_t)(col0 + rst) * ldb + gst8;

  const int nt = K >> 6;

  u16* pA0 = As;          u16* pA1 = As + 16384;  u16* pA2 = As + 32768;
  u16* pB0 = Bs;          u16* pB1 = Bs + 8192;   u16* pB2 = Bs + 16384;

  bf16x8 aF[4][2];   // a-frags of current tile, resident across 2 phases
  bf16x8 bF[2][2];   // b-frag pair, phase-local
  f32x4 accU[4][4] = {};
  f32x4 accG[4][4] = {};

#define STAGE_A(T, dst)                                                       \
  { const u16* g_ = gA + (size_t)(T) * 64;                                    \
    u16* d_ = (dst) + wave * 512;                                             \
    gld16(g_, d_);                                                            \
    gld16(g_ + (size_t)64 * lda, d_ + 4096);                                  \
    gld16(g_ + (size_t)128 * lda, d_ + 8192);                                 \
    gld16(g_ + (size_t)192 * lda, d_ + 12288); }

#define STAGE_B(T, dst)                                                       \
  { const u16* g_ = gB + (size_t)(T) * 64;                                    \
    u16* d_ = (dst) + wave * 512;                                             \
    gld16(g_, d_);                                                            \
    gld16(g_ + (size_t)64 * ldb, d_ + 4096); }

#define RD_A(pA)                                                              \
  _Pragma("unroll") for (int mi = 0; mi < 4; ++mi)                            \
  _Pragma("unroll") for (int ks = 0; ks < 2; ++ks)                            \
    aF[mi][ks] = *(const bf16x8*)&(pA)[(wm * 64 + mi * 16 + l16) * 64 +       \
                                       (((ks * 4 + quad) ^ xr) * 8)];

#define RD_B(pB, nip)                                                         \
  _Pragma("unroll") for (int nn = 0; nn < 2; ++nn)                            \
  _Pragma("unroll") for (int ks = 0; ks < 2; ++ks)                            \
    bF[nn][ks] = *(const bf16x8*)&(pB)[(wn * 64 + ((nip) * 2 + nn) * 16 + l16) * 64 + \
                                       (((ks * 4 + quad) ^ xr) * 8)];

#define QMM(ACC, nip)                                                         \
  _Pragma("unroll") for (int mi = 0; mi < 4; ++mi)                            \
  _Pragma("unroll") for (int nn = 0; nn < 2; ++nn) {                          \
    f32x4 c_ = ACC[mi][(nip) * 2 + nn];                                       \
    c_ = __builtin_amdgcn_mfma_f32_16x16x32_bf16(aF[mi][0], bF[nn][0], c_, 0, 0, 0); \
    c_ = __builtin_amdgcn_mfma_f32_16x16x32_bf16(aF[mi][1], bF[nn][1], c_, 0, 0, 0); \
    ACC[mi][(nip) * 2 + nn] = c_;                                             \
  }

#define WAITLG                                                                \
  asm volatile("s_waitcnt lgkmcnt(0)" ::: "memory");                          \
  __builtin_amdgcn_sched_barrier(0);

#define TILE2(ACC, i)                                                         \
  {                                                                           \
    const int T2 = 2 * (i) + 2, T3 = 2 * (i) + 3;                             \
    /* P1 */                                                                  \
    RD_A(pA0) RD_B(pB0, 0)                                                    \
    if (T2 < nt) STAGE_A(T2, pA2)                                             \
    __builtin_amdgcn_s_barrier();                                             \
    WAITLG                                                                    \
    __builtin_amdgcn_s_setprio(1); QMM(ACC, 0) __builtin_amdgcn_s_setprio(0); \
    __builtin_amdgcn_s_barrier();                                             \
    /* P2 */                                                                  \
    RD_B(pB0, 1)                                                              \
    if (T2 < nt) STAGE_B(T2, pB2)                                             \
    __builtin_amdgcn_s_barrier();                                             \
    WAITLG                                                                    \
    __builtin_amdgcn_s_setprio(1); QMM(ACC, 1) __builtin_amdgcn_s_setprio(0); \
    if (T2 < nt) { asm volatile("s_waitcnt vmcnt(6)" ::: "memory"); }         \
    else         { asm volatile("s_waitcnt vmcnt(0)" ::: "memory"); }         \
    __builtin_amdgcn_s_barrier();                                             \
    /* P3 */                                                                  \
    RD_A(pA1) RD_B(pB1, 0)                                                    \
    if (T3 < nt) STAGE_A(T3, pA0)                                             \
    __builtin_amdgcn_s_barrier();                                             \
    WAITLG                                                                    \
    __builtin_amdgcn_s_setprio(1); QMM(ACC, 0) __builtin_amdgcn_s_setprio(0); \
    __builtin_amdgcn_s_barrier();                                             \
    /* P4 */                                                                  \
    RD_B(pB1, 1)                                                              \
    if (T3 < nt) STAGE_B(T3, pB0)                                             \
    __builtin_amdgcn_s_barrier();                                             \
    WAITLG                                                                    \
    __builtin_amdgcn_s_setprio(1); QMM(ACC, 1) __builtin_amdgcn_s_setprio(0); \
    if (T3 < nt) { asm volatile("s_waitcnt vmcnt(6)" ::: "memory"); }         \
    else         { asm volatile("s_waitcnt vmcnt(0)" ::: "memory"); }         \
    __builtin_amdgcn_s_barrier();                                             \
    u16* tA_ = pA0; pA0 = pA2; pA2 = pA1; pA1 = tA_;                          \
    u16* tB_ = pB0; pB0 = pB2; pB2 = pB1; pB1 = tB_;                          \
  }

  // prologue: tiles 0,1 staged; wait tile 0 complete (leave tile 1's 6 in flight)
  STAGE_A(0, pA0) STAGE_B(0, pB0) STAGE_A(1, pA1) STAGE_B(1, pB1)
  asm volatile("s_waitcnt vmcnt(6)" ::: "memory");
  __builtin_amdgcn_s_barrier();

  const int nI = nt >> 1;
  if constexpr (EPI == 2) {
    const int nH = nI >> 1;
#pragma unroll 1
    for (int i = 0; i < nH; ++i) TILE2(accU, i)
#pragma unroll 1
    for (int i = nH; i < nI; ++i) TILE2(accG, i)
  } else {
#pragma unroll 1
    for (int i = 0; i < nI; ++i) TILE2(accU, i)
  }

  // ---------- epilogue ----------
  if constexpr (EPI == 2) {
    u16* outp; int ldo, c2;
    if (col0 < 8192) { outp = (u16*)C; ldo = 8192; c2 = col0; }
    else             { outp = C2;      ldo = 3840; c2 = 1024 + (col0 - 8192); }
#pragma unroll
    for (int mi = 0; mi < 4; ++mi)
#pragma unroll
      for (int ni = 0; ni < 4; ++ni)
#pragma unroll
        for (int r = 0; r < 4; ++r) {
          const float u = accU[mi][ni][r];
          const float gg = accG[mi][ni][r];
          const float val = u * gg / (1.0f + __expf(-gg));  // silu(g)*u
          const int gm = row0 + wm * 64 + mi * 16 + quad * 4 + r;
          const int gn = c2 + wn * 64 + ni * 16 + l16;
          outp[(size_t)gm * ldo + gn] = f2bf(val);
        }
  } else {
#pragma unroll
    for (int mi = 0; mi < 4; ++mi)
#pragma unroll
      for (int ni = 0; ni < 4; ++ni)
#pragma unroll
        for (int r = 0; r < 4; ++r) {
          const int gm = row0 + wm * 64 + mi * 16 + quad * 4 + r;
          const int gn = coff + col0 + wn * 64 + ni * 16 + l16;
          if constexpr (EPI == 0)
            ((u16*)C)[(size_t)gm * ldc + gn] = f2bf(accU[mi][ni][r]);
          else
            ((float*)C)[(size_t)gm * ldc + gn] = accU[mi][ni][r];
        }
  }
#undef STAGE_A
#undef STAGE_B
#undef RD_A
#undef RD_B
#undef QMM
#undef WAITLG
#undef TILE2
}

// ---------- launch ----------

extern "C" void kernel_launch(void* const* d_in, const int* in_sizes, int n_in,
                              void* d_out, int out_size, void* d_ws, size_t ws_size,
                              hipStream_t stream) {
  const float* x      = (const float*)d_in[0];
  const float* up_v   = (const float*)d_in[1];
  const float* up_u   = (const float*)d_in[2];
  const float* up_c   = (const float*)d_in[3];
  const float* gate_v = (const float*)d_in[4];
  const float* gate_u = (const float*)d_in[5];
  const float* gate_c = (const float*)d_in[6];
  const float* down_v = (const float*)d_in[7];
  const float* down_u = (const float*)d_in[8];
  const float* down_c = (const float*)d_in[9];
  const int* svd_up   = (const int*)d_in[10];
  const int* col_up   = (const int*)d_in[11];
  const int* svd_gate = (const int*)d_in[12];
  const int* col_gate = (const int*)d_in[13];
  const int* svd_down = (const int*)d_in[14];
  const int* col_down = (const int*)d_in[15];

  char* ws = (char*)d_ws;
  // XG [8192,6144] (100.7MB) aliases Gsvd [8192,8192] (134.2MB): XG dead before Gsvd written.
  u16* XG     = (u16*)(ws + 0);
  u16* Gsvd   = (u16*)(ws + 0);
  u16* Afused = (u16*)(ws + 134217728);  // [8192,4096] 67.1MB
  u16* Afin   = (u16*)(ws + 201326592);  // [8192,3840] 62.9MB
  u16* V1     = (u16*)(ws + 264241152);  // [2048,3072] 12.6MB  (V1u rows 0:1024, V1g rows 1024:2048)
  u16* Wf     = (u16*)(ws + 276824064);  // [11008,4096] 90.2MB
  u16* DV     = (u16*)(ws + 367001600);  // [1024,8192] 16.8MB
  u16* W2     = (u16*)(ws + 383778816);  // [4096,3840] 31.5MB  (total ~396MiB)

  const dim3 blk(256);
  const dim3 blk512(512);
  const int BIG = 1 << 30;

  // phase 0: gathers + weight prep (independent)
  gather_x2<<<dim3(8192), blk, 0, stream>>>(x, svd_up, col_up, svd_gate, col_gate, XG, Afused);
  cast_bf16_vec<<<dim3(3072), blk, 0, stream>>>(up_v, V1, 1024 * 3072 / 4);
  cast_bf16_vec<<<dim3(3072), blk, 0, stream>>>(gate_v, V1 + 1024 * 3072, 1024 * 3072 / 4);
  cast_bf16_vec<<<dim3(8192), blk, 0, stream>>>(down_v, DV, 1024 * 8192 / 4);
  build_wfused<<<dim3(11008), blk, 0, stream>>>(up_u, up_c, gate_u, gate_c, svd_down, col_down, Wf);
  build_wdown2<<<dim3(4096), blk, 0, stream>>>(down_u, down_c, W2);

  // phase 1 (merged): t_up (bx<8) and t_gate (bx>=8); M=8192, N=1024 each, K=3072
  gemm256<0><<<dim3(16, 32), blk512, 0, stream>>>(
      XG, 6144, V1, 3072, 3072, Afused, 4096, 0, nullptr,
      XG + 3072, V1 + 1024 * 3072, 8, 2048);

  // phase 2: fused up/gate stage-2 + SwiGLU (M=8192, N=11008, K=2048+2048), swizzled grid
  gemm256<2><<<dim3(86 * 32), blk512, 0, stream>>>(
      Afused, 4096, Wf, 4096, 4096, Gsvd, 0, 0, Afin, nullptr, nullptr, BIG, 0);

  // phase 3: t2 = Gsvd @ down_v^T (M=8192, N=1024, K=8192) -> Afin cols 0:1024
  gemm256<0><<<dim3(8, 32), blk512, 0, stream>>>(
      Gsvd, 8192, DV, 8192, 8192, Afin, 3840, 0, nullptr, nullptr, nullptr, BIG, 0);

  // phase 4: out = Afin @ W2^T (M=8192, N=4096, K=3840), fp32 -> d_out
  gemm256<1><<<dim3(32, 32), blk512, 0, stream>>>(
      Afin, 3840, W2, 3840, 3840, d_out, 4096, 0, nullptr, nullptr, nullptr, BIG, 0);
}